// Round 11
// baseline (89.375 us; speedup 1.0000x reference)
//
#include <hip/hip_runtime.h>
#include <cstdint>
#include <cstddef>

// Problem dims
constexpr int Bv = 4096;   // batch
constexpr int Dv = 1024;   // feature dim
constexpr int Cv = 1000;   // classes
constexpr int Tv = 32;     // trees
constexpr int NI = 63;     // internal nodes per tree
constexpr int NL = 64;     // leaves per tree
constexpr int TNp = 2048;  // padded node dim: tree t at cols [64t, 64t+63]
constexpr int TL = Tv * NL;   // 2048
constexpr int Npad = 1024;    // padded class dim

typedef _Float16 h8  __attribute__((ext_vector_type(8)));
typedef _Float16 h4  __attribute__((ext_vector_type(4)));
typedef short    s8v __attribute__((ext_vector_type(8)));
typedef unsigned short us8 __attribute__((ext_vector_type(8)));
typedef float    f4v __attribute__((ext_vector_type(4)));

// ---------------------------------------------------------------------------
// Workspace layout (float units).
// ---------------------------------------------------------------------------
constexpr size_t N_X    = (size_t)Bv * Dv;                 // 4M elems
constexpr size_t N_W    = (size_t)TNp * Dv;                // 2M elems (padded)
constexpr size_t OFF_XH = 64;                              // f16 [Bv][Dv]
constexpr size_t OFF_WH = OFF_XH + N_X / 2;                // f16 [TNp][Dv]
constexpr size_t OFF_MH = OFF_WH + N_W / 2;                // bf16 [Bv][TL]
constexpr size_t OFF_PTH= OFF_MH + (size_t)Bv * TL / 2;    // bf16 [Npad][TL]

// bf16 round-to-nearest-even from fp32
__device__ __forceinline__ unsigned short f2bf_rn(float x) {
    unsigned u = __float_as_uint(x);
    return (unsigned short)((u + 0x7fffu + ((u >> 16) & 1u)) >> 16);
}

// async global->LDS, 16B per lane, LDS dest = wave-uniform base + lane*16
__device__ __forceinline__ void gll16(const void* gptr, void* lptr) {
    __builtin_amdgcn_global_load_lds(
        (const __attribute__((address_space(1))) unsigned int*)gptr,
        (__attribute__((address_space(3))) unsigned int*)lptr,
        16, 0, 0);
}

// ---------------------------------------------------------------------------
// Kernel A (grid-sectioned, all sections independent):
//   blocks [0, 4096)     : x fp32 -> Xh f16
//   blocks [4096, 6144)  : W re-pack rows (t*63+i)->(t*64+i), f16, pad 0
//   blocks [6144, 6400)  : leaf softmax (8 rows/block) -> PTH bf16 TRANSPOSED
//                          directly (kills fp32 P buffer + separate tp pass)
// ---------------------------------------------------------------------------
__global__ __launch_bounds__(256)
void k_prep_leaf(const float* __restrict__ x, const float* __restrict__ sw,
                 const float* __restrict__ ll, const float* __restrict__ lt,
                 _Float16* __restrict__ Xh, _Float16* __restrict__ Wh,
                 unsigned short* __restrict__ PTH) {
    // leafsm scratch: T[8][1024] f32 + rs[8]. Stride 1024 is conflict-free
    // here: every access indexes by per-lane c (64 lanes -> 2/bank = free).
    // (Round-10 bug: stride 1009 < 1024 made rows overlap.)
    __shared__ __align__(16) char lds[8 * 1024 * 4 + 32];

    const int b = blockIdx.x;
    const int tid = threadIdx.x;
    if (b < 4096) {
        const size_t i4 = ((size_t)b * 256 + tid) * 4;
        const float4 v = *reinterpret_cast<const float4*>(&x[i4]);
        h4 vh;
        vh[0] = (_Float16)v.x; vh[1] = (_Float16)v.y;
        vh[2] = (_Float16)v.z; vh[3] = (_Float16)v.w;
        *reinterpret_cast<h4*>(&Xh[i4]) = vh;
    } else if (b < 6144) {
        const size_t d4 = ((size_t)(b - 4096) * 256 + tid) * 4;
        const int row = (int)(d4 >> 10);
        const int col = (int)(d4 & 1023);
        const int t = row >> 6, i = row & 63;
        float4 v = make_float4(0.f, 0.f, 0.f, 0.f);
        if (i < NI)
            v = *reinterpret_cast<const float4*>(&sw[(size_t)(t * NI + i) * Dv + col]);
        h4 vh;
        vh[0] = (_Float16)v.x; vh[1] = (_Float16)v.y;
        vh[2] = (_Float16)v.z; vh[3] = (_Float16)v.w;
        *reinterpret_cast<h4*>(&Wh[d4]) = vh;
    } else {
        // ---- leaf softmax, 8 rows per block, direct transposed bf16 out ----
        const int blk = b - 6144;          // 0..255
        const int r0 = blk * 8;            // leaf-row base (k dim of PTH)
        const float temp = fminf(fmaxf(expf(lt[0]), 0.1f), 5.0f);
        const float invT = 1.0f / temp;
        float* T  = (float*)lds;           // [8][1024]
        float* rs = (float*)(lds + 8 * 1024 * 4);  // [8]

        #pragma unroll
        for (int rr = 0; rr < 8; ++rr) {
            for (int c = tid; c < 1024; c += 256)
                T[rr * 1024 + c] = (c < Cv) ? ll[(size_t)(r0 + rr) * Cv + c] * invT
                                            : -3.4e38f;
        }
        __syncthreads();

        const int wv = tid >> 6, lane = tid & 63;
        #pragma unroll
        for (int rw = 0; rw < 2; ++rw) {
            const int rr = wv * 2 + rw;
            float m = -3.4e38f;
            for (int c = lane; c < 1024; c += 64) m = fmaxf(m, T[rr * 1024 + c]);
            #pragma unroll
            for (int o = 32; o > 0; o >>= 1) m = fmaxf(m, __shfl_xor(m, o));
            float s = 0.f;
            for (int c = lane; c < 1024; c += 64) {
                const float e = __expf(T[rr * 1024 + c] - m);
                T[rr * 1024 + c] = e;
                s += e;
            }
            #pragma unroll
            for (int o = 32; o > 0; o >>= 1) s += __shfl_xor(s, o);
            if (lane == 0) rs[rr] = 1.0f / s;
        }
        __syncthreads();

        // transposed write: PTH[c][r0..r0+7] as one us8 per class c
        for (int c = tid; c < 1024; c += 256) {
            us8 v;
            #pragma unroll
            for (int rr = 0; rr < 8; ++rr) {
                const float f = (c < Cv) ? T[rr * 1024 + c] * rs[rr] : 0.f;
                v[rr] = f2bf_rn(f);
            }
            *reinterpret_cast<us8*>(&PTH[(size_t)c * TL + r0]) = v;
        }
    }
}

// ---------------------------------------------------------------------------
// GEMM1+mu fused (round-9 proven structure): 128x128 tile, BK=32, 4 waves 2x2,
// both operands via global_load_lds dbuf, counted vmcnt(4). Epilogue sigmoid
// stored as f16 LDS scratch (33.3 KB union -> 4 blocks/CU, 16 waves/CU).
// ---------------------------------------------------------------------------
__global__ __launch_bounds__(256, 4)
void k_gemm1mu(const _Float16* __restrict__ Xh, const _Float16* __restrict__ Wh,
               const float* __restrict__ bias, const float* __restrict__ tw,
               const float* __restrict__ lt, unsigned short* __restrict__ MH) {
    __shared__ __align__(16) char lds[33280];

    const int tid = threadIdx.x;
    // XCD swizzle: 512 wgs, 8 chunks of 64 = 16(by) x 4(bx) sub-blocks
    const int wg  = (blockIdx.x & 7) * 64 + (blockIdx.x >> 3);
    const int blk = wg >> 6;
    const int j   = wg & 63;
    const int bx  = (blk & 3) * 4 + (j & 3);       // 0..15
    const int by  = (blk >> 2) * 16 + (j >> 2);    // 0..31
    const int bm = by * 128, bn = bx * 128;

    const int lane = tid & 63, wv = tid >> 6;
    const int wr = wv >> 1, wc = wv & 1;
    const int lrow = lane & 15, kg = (lane >> 4) * 8;
    const int sr = lane >> 2;            // staging row within 16-row chunk
    const int sc = (lane & 3) * 8;       // staging f16 col (0,8,16,24)

    // scalars inline
    const float temp = fminf(fmaxf(expf(lt[0]), 0.1f), 5.0f);
    const float invT = 1.0f / temp;
    const int mytree = 2 * bx + wc;
    float wm = -3.4e38f;
    #pragma unroll
    for (int t = 0; t < Tv; ++t) wm = fmaxf(wm, tw[t]);
    float wsum = 0.f, wmine = 0.f;
    #pragma unroll
    for (int t = 0; t < Tv; ++t) {
        const float e = expf(tw[t] - wm);
        wsum += e;
        if (t == mytree) wmine = e;
    }
    const float wt = wmine / wsum;

    f4v acc[4][4] = {};

#define STG(bufi, k0)                                                         \
    { _Pragma("unroll")                                                       \
      for (int i_ = 0; i_ < 2; ++i_) {                                        \
        const int ch_  = wv * 2 + i_;                                         \
        const int row_ = ch_ * 16 + sr;                                       \
        gll16(&Xh[(size_t)(bm + row_) * Dv + (k0) + sc],                      \
              lds + (bufi) * 16384 + ch_ * 1024);                             \
        gll16(&Wh[(size_t)(bn + row_) * Dv + (k0) + sc],                      \
              lds + (bufi) * 16384 + 8192 + ch_ * 1024);                      \
      } }

    STG(0, 0);
    for (int t = 0; t < 32; ++t) {
        const int cur = t & 1;
        if (t < 31) {
            STG(cur ^ 1, (t + 1) * 32);
            asm volatile("s_waitcnt vmcnt(4)" ::: "memory");
        } else {
            asm volatile("s_waitcnt vmcnt(0)" ::: "memory");
        }
        __builtin_amdgcn_s_barrier();
        __builtin_amdgcn_sched_barrier(0);

        h8 a[4], b[4];
        #pragma unroll
        for (int mf = 0; mf < 4; ++mf)
            a[mf] = *reinterpret_cast<const h8*>(
                lds + cur * 16384 + ((wr * 64 + mf * 16 + lrow) * 32 + kg) * 2);
        #pragma unroll
        for (int nf = 0; nf < 4; ++nf)
            b[nf] = *reinterpret_cast<const h8*>(
                lds + cur * 16384 + 8192 + ((wc * 64 + nf * 16 + lrow) * 32 + kg) * 2);
        #pragma unroll
        for (int mf = 0; mf < 4; ++mf)
            #pragma unroll
            for (int nf = 0; nf < 4; ++nf)
                acc[mf][nf] = __builtin_amdgcn_mfma_f32_16x16x32_f16(a[mf], b[nf], acc[mf][nf], 0, 0, 0);

        __builtin_amdgcn_sched_barrier(0);
        asm volatile("s_waitcnt lgkmcnt(0)" ::: "memory");
        __builtin_amdgcn_s_barrier();
    }
#undef STG

    // ---- epilogue: sigmoid -> per-wave [64 rows][65] f16 scratch ----
    _Float16* scr = (_Float16*)lds + wv * (64 * 65);
    #pragma unroll
    for (int nf = 0; nf < 4; ++nf) {
        const int colB = nf * 16 + lrow;                 // node idx 0..63
        const int gcol = bn + wc * 64 + colB;
        const int ii = gcol & 63;
        const float bv = (ii < NI) ? bias[(gcol >> 6) * NI + ii] : 0.f;
        #pragma unroll
        for (int mf = 0; mf < 4; ++mf) {
            #pragma unroll
            for (int r = 0; r < 4; ++r) {
                const int rowB = mf * 16 + (lane >> 4) * 4 + r;
                const float z = (acc[mf][nf][r] + bv) * invT;
                scr[rowB * 65 + colB] = (_Float16)(1.0f / (1.0f + __expf(-z)));
            }
        }
    }
    asm volatile("s_waitcnt lgkmcnt(0)" ::: "memory");

    // ---- per-lane mu: row = lane, tree = mytree ----
    const _Float16* srow = scr + lane * 65;
    float mu[NL];
    mu[0] = wt;
    #pragma unroll
    for (int d = 0; d < 6; ++d) {
        const int width = 1 << d;
        #pragma unroll
        for (int i = width - 1; i >= 0; --i) {
            const float sv = (float)srow[width - 1 + i];
            const float m  = mu[i];
            mu[2 * i + 1] = m * sv;
            mu[2 * i]     = m * (1.0f - sv);
        }
    }
    const size_t obase = (size_t)(bm + wr * 64 + lane) * TL + (size_t)mytree * 64;
    #pragma unroll
    for (int c = 0; c < 8; ++c) {
        us8 vh;
        #pragma unroll
        for (int jj = 0; jj < 8; ++jj) vh[jj] = f2bf_rn(mu[c * 8 + jj]);
        *reinterpret_cast<us8*>(&MH[obase + c * 8]) = vh;
    }
}

// ---------------------------------------------------------------------------
// GEMM2 (single-pass bf16, split-K-in-block): out = muw @ P.
// A = MH [Bv][TL], B = PTH [Npad][TL]. 128x64 tile, grid 512 (2 blocks/CU,
// 8 waves/CU). 4 waves = 2 M-halves x 2 K-halves; each wave owns a 64x64
// sub-tile over half of BK=64 -> 8 ds_read_b128 vs 16 MFMA per iter.
// Cross-K reduce through LDS at the end.
// ---------------------------------------------------------------------------
__global__ __launch_bounds__(256, 2)
void k_gemm2(const unsigned short* __restrict__ MH, const unsigned short* __restrict__ PTH,
             float* __restrict__ out) {
    // 2 bufs x (A 128x64 bf16 16KB + B 64x64 bf16 8KB) = 48 KB
    // epilogue reduce reuses first 32 KB ([2 wr][64][64] f32)
    __shared__ __align__(16) char lds[49152];

    const int tid  = threadIdx.x;
    const int wg  = (blockIdx.x & 7) * 64 + (blockIdx.x >> 3);
    const int blk = wg >> 6;                        // 0..7
    const int j   = wg & 63;
    const int bnt = (blk & 1) * 8 + (j & 7);        // 0..15
    const int bmt = (blk >> 1) * 8 + (j >> 3);      // 0..31
    const int bm = bmt * 128, bn = bnt * 64;

    const int lane = tid & 63;
    const int wv   = tid >> 6;
    const int wr   = wv >> 1;            // M-half
    const int wk   = wv & 1;             // K-half
    const int lrow = lane & 15;
    const int kg   = (lane >> 4) * 8;
    const int sr   = lane >> 3;          // staging row within 8-row chunk
    const int sc   = (lane & 7) * 8;     // staging bf16 col (0..56)

    f4v acc[4][4] = {};

    // A: 16 chunks of 1KB (4/wave); B: 8 chunks (2/wave) -> 6 gll16/wave
#define STG2(bufi, k0)                                                        \
    { _Pragma("unroll")                                                       \
      for (int i_ = 0; i_ < 4; ++i_) {                                        \
        const int ch_  = wv * 4 + i_;                                         \
        const int row_ = ch_ * 8 + sr;                                        \
        gll16(&MH[(size_t)(bm + row_) * TL + (k0) + sc],                      \
              lds + (bufi) * 24576 + ch_ * 1024);                             \
      }                                                                       \
      _Pragma("unroll")                                                       \
      for (int i_ = 0; i_ < 2; ++i_) {                                        \
        const int ch_  = wv * 2 + i_;                                         \
        const int row_ = ch_ * 8 + sr;                                        \
        gll16(&PTH[(size_t)(bn + row_) * TL + (k0) + sc],                     \
              lds + (bufi) * 24576 + 16384 + ch_ * 1024);                     \
      } }

    STG2(0, 0);
    for (int t = 0; t < 32; ++t) {
        const int cur = t & 1;
        if (t < 31) {
            STG2(cur ^ 1, (t + 1) * 64);
            asm volatile("s_waitcnt vmcnt(6)" ::: "memory");
        } else {
            asm volatile("s_waitcnt vmcnt(0)" ::: "memory");
        }
        __builtin_amdgcn_s_barrier();
        __builtin_amdgcn_sched_barrier(0);

        s8v a[4], bfr[4];
        #pragma unroll
        for (int mf = 0; mf < 4; ++mf)
            a[mf] = *reinterpret_cast<const s8v*>(
                lds + cur * 24576 + ((wr * 64 + mf * 16 + lrow) * 64 + wk * 32 + kg) * 2);
        #pragma unroll
        for (int nf = 0; nf < 4; ++nf)
            bfr[nf] = *reinterpret_cast<const s8v*>(
                lds + cur * 24576 + 16384 + ((nf * 16 + lrow) * 64 + wk * 32 + kg) * 2);
        #pragma unroll
        for (int mf = 0; mf < 4; ++mf)
            #pragma unroll
            for (int nf = 0; nf < 4; ++nf)
                acc[mf][nf] = __builtin_amdgcn_mfma_f32_16x16x32_bf16(a[mf], bfr[nf], acc[mf][nf], 0, 0, 0);

        __builtin_amdgcn_sched_barrier(0);
        asm volatile("s_waitcnt lgkmcnt(0)" ::: "memory");
        __builtin_amdgcn_s_barrier();
    }
#undef STG2

    // ---- cross-K reduce: wk==1 waves dump acc, wk==0 waves add + write ----
    float* red = (float*)lds;   // [2 wr][64][64] f32 = 32 KB
    if (wk == 1) {
        #pragma unroll
        for (int mf = 0; mf < 4; ++mf)
            #pragma unroll
            for (int nf = 0; nf < 4; ++nf)
                #pragma unroll
                for (int r = 0; r < 4; ++r) {
                    const int rowB = mf * 16 + (lane >> 4) * 4 + r;
                    const int colB = nf * 16 + lrow;
                    red[wr * 4096 + rowB * 64 + colB] = acc[mf][nf][r];
                }
    }
    __syncthreads();
    if (wk == 0) {
        #pragma unroll
        for (int nf = 0; nf < 4; ++nf) {
            const int col = bn + nf * 16 + lrow;
            if (col >= Cv) continue;
            #pragma unroll
            for (int mf = 0; mf < 4; ++mf) {
                #pragma unroll
                for (int r = 0; r < 4; ++r) {
                    const int rowB = mf * 16 + (lane >> 4) * 4 + r;
                    const float v = acc[mf][nf][r] + red[wr * 4096 + rowB * 64 + nf * 16 + lrow];
                    out[(size_t)(bm + wr * 64 + rowB) * Cv + col] = v;
                }
            }
        }
    }
}

// ---------------------------------------------------------------------------
extern "C" void kernel_launch(void* const* d_in, const int* in_sizes, int n_in,
                              void* d_out, int out_size, void* d_ws, size_t ws_size,
                              hipStream_t stream) {
    const float* x  = (const float*)d_in[0];  // [B, D]
    const float* sw = (const float*)d_in[1];  // [T, NI, D]
    const float* sb = (const float*)d_in[2];  // [T, NI]
    const float* ll = (const float*)d_in[3];  // [T, NL, C]
    const float* tw = (const float*)d_in[4];  // [T]
    const float* lt = (const float*)d_in[5];  // scalar

    float* out  = (float*)d_out;              // [B, C]
    float* ws   = (float*)d_ws;
    _Float16* Xh = (_Float16*)(ws + OFF_XH);
    _Float16* Wh = (_Float16*)(ws + OFF_WH);
    unsigned short* MH  = (unsigned short*)(ws + OFF_MH);
    unsigned short* PTH = (unsigned short*)(ws + OFF_PTH);

    k_prep_leaf<<<6400, 256, 0, stream>>>(x, sw, ll, lt, Xh, Wh, PTH);
    k_gemm1mu<<<512, 256, 0, stream>>>(Xh, Wh, sb, tw, lt, MH);
    k_gemm2<<<512, 256, 0, stream>>>(MH, PTH, out);
}

// Round 12
// 72.528 us; speedup vs baseline: 1.2323x; 1.2323x over previous
//
#include <hip/hip_runtime.h>
#include <cstdint>
#include <cstddef>

// Problem dims
constexpr int Bv = 4096;   // batch
constexpr int Dv = 1024;   // feature dim
constexpr int Cv = 1000;   // classes
constexpr int Tv = 32;     // trees
constexpr int NI = 63;     // internal nodes per tree
constexpr int NL = 64;     // leaves per tree
constexpr int TNp = 2048;  // padded node dim: tree t at cols [64t, 64t+63]
constexpr int TL = Tv * NL;   // 2048
constexpr int Npad = 1024;    // padded class dim

typedef _Float16 h8  __attribute__((ext_vector_type(8)));
typedef _Float16 h4  __attribute__((ext_vector_type(4)));
typedef short    s8v __attribute__((ext_vector_type(8)));
typedef unsigned short us8 __attribute__((ext_vector_type(8)));
typedef float    f4v __attribute__((ext_vector_type(4)));

// ---------------------------------------------------------------------------
// Workspace layout (float units).
// ---------------------------------------------------------------------------
constexpr size_t N_X    = (size_t)Bv * Dv;                 // 4M elems
constexpr size_t N_W    = (size_t)TNp * Dv;                // 2M elems (padded)
constexpr size_t OFF_XH = 64;                              // f16 [Bv][Dv]
constexpr size_t OFF_WH = OFF_XH + N_X / 2;                // f16 [TNp][Dv]
constexpr size_t OFF_MH = OFF_WH + N_W / 2;                // bf16 [Bv][TL]
constexpr size_t OFF_PTH= OFF_MH + (size_t)Bv * TL / 2;    // bf16 [Npad][TL]

// bf16 round-to-nearest-even from fp32
__device__ __forceinline__ unsigned short f2bf_rn(float x) {
    unsigned u = __float_as_uint(x);
    return (unsigned short)((u + 0x7fffu + ((u >> 16) & 1u)) >> 16);
}

// async global->LDS, 16B per lane, LDS dest = wave-uniform base + lane*16
__device__ __forceinline__ void gll16(const void* gptr, void* lptr) {
    __builtin_amdgcn_global_load_lds(
        (const __attribute__((address_space(1))) unsigned int*)gptr,
        (__attribute__((address_space(3))) unsigned int*)lptr,
        16, 0, 0);
}

// ---------------------------------------------------------------------------
// Kernel A — pure streaming, ZERO LDS (full occupancy):
//   blocks [0, 4096)     : x fp32 -> Xh f16
//   blocks [4096, 6144)  : W re-pack rows (t*63+i)->(t*64+i), f16, pad 0
// ---------------------------------------------------------------------------
__global__ __launch_bounds__(256)
void k_prep(const float* __restrict__ x, const float* __restrict__ sw,
            _Float16* __restrict__ Xh, _Float16* __restrict__ Wh) {
    const int b = blockIdx.x;
    const int tid = threadIdx.x;
    if (b < 4096) {
        const size_t i4 = ((size_t)b * 256 + tid) * 4;
        const float4 v = *reinterpret_cast<const float4*>(&x[i4]);
        h4 vh;
        vh[0] = (_Float16)v.x; vh[1] = (_Float16)v.y;
        vh[2] = (_Float16)v.z; vh[3] = (_Float16)v.w;
        *reinterpret_cast<h4*>(&Xh[i4]) = vh;
    } else {
        const size_t d4 = ((size_t)(b - 4096) * 256 + tid) * 4;
        const int row = (int)(d4 >> 10);
        const int col = (int)(d4 & 1023);
        const int t = row >> 6, i = row & 63;
        float4 v = make_float4(0.f, 0.f, 0.f, 0.f);
        if (i < NI)
            v = *reinterpret_cast<const float4*>(&sw[(size_t)(t * NI + i) * Dv + col]);
        h4 vh;
        vh[0] = (_Float16)v.x; vh[1] = (_Float16)v.y;
        vh[2] = (_Float16)v.z; vh[3] = (_Float16)v.w;
        *reinterpret_cast<h4*>(&Wh[d4]) = vh;
    }
}

// ---------------------------------------------------------------------------
// Kernel B (grid-sectioned):
//   blocks [0, 512)   : GEMM1+mu fused (round-9 proven): 128x128 tile, BK=32,
//                       4 waves 2x2, global_load_lds dbuf, counted vmcnt(4),
//                       sigmoid -> f16 LDS scratch -> per-lane path product
//                       -> MH bf16. 33.3 KB union -> 4 blocks/CU.
//   blocks [512, 768) : leaf softmax (8 rows/block) -> PTH bf16 TRANSPOSED
//                       directly (round-11 verified section; rider blocks,
//                       independent of prep outputs).
// ---------------------------------------------------------------------------
__global__ __launch_bounds__(256, 4)
void k_gemm1mu_lf(const _Float16* __restrict__ Xh, const _Float16* __restrict__ Wh,
                  const float* __restrict__ bias, const float* __restrict__ tw,
                  const float* __restrict__ lt, const float* __restrict__ ll,
                  unsigned short* __restrict__ MH, unsigned short* __restrict__ PTH) {
    __shared__ __align__(16) char lds[33280];

    const int tid = threadIdx.x;

    if (blockIdx.x >= 512) {
        // ---- leaf softmax, 8 rows per block, direct transposed bf16 out ----
        const int blk = blockIdx.x - 512;  // 0..255
        const int r0 = blk * 8;            // leaf-row base (k dim of PTH)
        const float temp = fminf(fmaxf(expf(lt[0]), 0.1f), 5.0f);
        const float invT = 1.0f / temp;
        float* T  = (float*)lds;           // [8][1024] = 32 KB
        float* rs = (float*)(lds + 8 * 1024 * 4);  // [8]

        #pragma unroll
        for (int rr = 0; rr < 8; ++rr) {
            for (int c = tid; c < 1024; c += 256)
                T[rr * 1024 + c] = (c < Cv) ? ll[(size_t)(r0 + rr) * Cv + c] * invT
                                            : -3.4e38f;
        }
        __syncthreads();

        const int wvl = tid >> 6, lane = tid & 63;
        #pragma unroll
        for (int rw = 0; rw < 2; ++rw) {
            const int rr = wvl * 2 + rw;
            float m = -3.4e38f;
            for (int c = lane; c < 1024; c += 64) m = fmaxf(m, T[rr * 1024 + c]);
            #pragma unroll
            for (int o = 32; o > 0; o >>= 1) m = fmaxf(m, __shfl_xor(m, o));
            float s = 0.f;
            for (int c = lane; c < 1024; c += 64) {
                const float e = __expf(T[rr * 1024 + c] - m);
                T[rr * 1024 + c] = e;
                s += e;
            }
            #pragma unroll
            for (int o = 32; o > 0; o >>= 1) s += __shfl_xor(s, o);
            if (lane == 0) rs[rr] = 1.0f / s;
        }
        __syncthreads();

        // transposed write: PTH[c][r0..r0+7] as one us8 per class c
        for (int c = tid; c < 1024; c += 256) {
            us8 v;
            #pragma unroll
            for (int rr = 0; rr < 8; ++rr) {
                const float f = (c < Cv) ? T[rr * 1024 + c] * rs[rr] : 0.f;
                v[rr] = f2bf_rn(f);
            }
            *reinterpret_cast<us8*>(&PTH[(size_t)c * TL + r0]) = v;
        }
        return;
    }

    // ---------------- GEMM1+mu section (round-9 verbatim) ----------------
    // XCD swizzle: 512 wgs, 8 chunks of 64 = 16(by) x 4(bx) sub-blocks
    const int wg  = (blockIdx.x & 7) * 64 + (blockIdx.x >> 3);
    const int blk = wg >> 6;
    const int j   = wg & 63;
    const int bx  = (blk & 3) * 4 + (j & 3);       // 0..15
    const int by  = (blk >> 2) * 16 + (j >> 2);    // 0..31
    const int bm = by * 128, bn = bx * 128;

    const int lane = tid & 63, wv = tid >> 6;
    const int wr = wv >> 1, wc = wv & 1;
    const int lrow = lane & 15, kg = (lane >> 4) * 8;
    const int sr = lane >> 2;            // staging row within 16-row chunk
    const int sc = (lane & 3) * 8;       // staging f16 col (0,8,16,24)

    // scalars inline
    const float temp = fminf(fmaxf(expf(lt[0]), 0.1f), 5.0f);
    const float invT = 1.0f / temp;
    const int mytree = 2 * bx + wc;
    float wm = -3.4e38f;
    #pragma unroll
    for (int t = 0; t < Tv; ++t) wm = fmaxf(wm, tw[t]);
    float wsum = 0.f, wmine = 0.f;
    #pragma unroll
    for (int t = 0; t < Tv; ++t) {
        const float e = expf(tw[t] - wm);
        wsum += e;
        if (t == mytree) wmine = e;
    }
    const float wt = wmine / wsum;

    f4v acc[4][4] = {};

#define STG(bufi, k0)                                                         \
    { _Pragma("unroll")                                                       \
      for (int i_ = 0; i_ < 2; ++i_) {                                        \
        const int ch_  = wv * 2 + i_;                                         \
        const int row_ = ch_ * 16 + sr;                                       \
        gll16(&Xh[(size_t)(bm + row_) * Dv + (k0) + sc],                      \
              lds + (bufi) * 16384 + ch_ * 1024);                             \
        gll16(&Wh[(size_t)(bn + row_) * Dv + (k0) + sc],                      \
              lds + (bufi) * 16384 + 8192 + ch_ * 1024);                      \
      } }

    STG(0, 0);
    for (int t = 0; t < 32; ++t) {
        const int cur = t & 1;
        if (t < 31) {
            STG(cur ^ 1, (t + 1) * 32);
            asm volatile("s_waitcnt vmcnt(4)" ::: "memory");
        } else {
            asm volatile("s_waitcnt vmcnt(0)" ::: "memory");
        }
        __builtin_amdgcn_s_barrier();
        __builtin_amdgcn_sched_barrier(0);

        h8 a[4], b[4];
        #pragma unroll
        for (int mf = 0; mf < 4; ++mf)
            a[mf] = *reinterpret_cast<const h8*>(
                lds + cur * 16384 + ((wr * 64 + mf * 16 + lrow) * 32 + kg) * 2);
        #pragma unroll
        for (int nf = 0; nf < 4; ++nf)
            b[nf] = *reinterpret_cast<const h8*>(
                lds + cur * 16384 + 8192 + ((wc * 64 + nf * 16 + lrow) * 32 + kg) * 2);
        #pragma unroll
        for (int mf = 0; mf < 4; ++mf)
            #pragma unroll
            for (int nf = 0; nf < 4; ++nf)
                acc[mf][nf] = __builtin_amdgcn_mfma_f32_16x16x32_f16(a[mf], b[nf], acc[mf][nf], 0, 0, 0);

        __builtin_amdgcn_sched_barrier(0);
        asm volatile("s_waitcnt lgkmcnt(0)" ::: "memory");
        __builtin_amdgcn_s_barrier();
    }
#undef STG

    // ---- epilogue: sigmoid -> per-wave [64 rows][65] f16 scratch ----
    _Float16* scr = (_Float16*)lds + wv * (64 * 65);
    #pragma unroll
    for (int nf = 0; nf < 4; ++nf) {
        const int colB = nf * 16 + lrow;                 // node idx 0..63
        const int gcol = bn + wc * 64 + colB;
        const int ii = gcol & 63;
        const float bv = (ii < NI) ? bias[(gcol >> 6) * NI + ii] : 0.f;
        #pragma unroll
        for (int mf = 0; mf < 4; ++mf) {
            #pragma unroll
            for (int r = 0; r < 4; ++r) {
                const int rowB = mf * 16 + (lane >> 4) * 4 + r;
                const float z = (acc[mf][nf][r] + bv) * invT;
                scr[rowB * 65 + colB] = (_Float16)(1.0f / (1.0f + __expf(-z)));
            }
        }
    }
    asm volatile("s_waitcnt lgkmcnt(0)" ::: "memory");

    // ---- per-lane mu: row = lane, tree = mytree ----
    const _Float16* srow = scr + lane * 65;
    float mu[NL];
    mu[0] = wt;
    #pragma unroll
    for (int d = 0; d < 6; ++d) {
        const int width = 1 << d;
        #pragma unroll
        for (int i = width - 1; i >= 0; --i) {
            const float sv = (float)srow[width - 1 + i];
            const float m  = mu[i];
            mu[2 * i + 1] = m * sv;
            mu[2 * i]     = m * (1.0f - sv);
        }
    }
    const size_t obase = (size_t)(bm + wr * 64 + lane) * TL + (size_t)mytree * 64;
    #pragma unroll
    for (int c = 0; c < 8; ++c) {
        us8 vh;
        #pragma unroll
        for (int jj = 0; jj < 8; ++jj) vh[jj] = f2bf_rn(mu[c * 8 + jj]);
        *reinterpret_cast<us8*>(&MH[obase + c * 8]) = vh;
    }
}

// ---------------------------------------------------------------------------
// GEMM2 (single-pass bf16, split-K-in-block, round-11 verified): out = muw @ P.
// A = MH [Bv][TL], B = PTH [Npad][TL]. 128x64 tile, grid 512 (2 blocks/CU,
// 8 waves/CU). 4 waves = 2 M-halves x 2 K-halves; each wave owns a 64x64
// sub-tile over half of BK=64 -> 8 ds_read_b128 vs 16 MFMA per iter.
// Cross-K reduce through LDS at the end.
// ---------------------------------------------------------------------------
__global__ __launch_bounds__(256, 2)
void k_gemm2(const unsigned short* __restrict__ MH, const unsigned short* __restrict__ PTH,
             float* __restrict__ out) {
    // 2 bufs x (A 128x64 bf16 16KB + B 64x64 bf16 8KB) = 48 KB
    // epilogue reduce reuses first 32 KB ([2 wr][64][64] f32)
    __shared__ __align__(16) char lds[49152];

    const int tid  = threadIdx.x;
    const int wg  = (blockIdx.x & 7) * 64 + (blockIdx.x >> 3);
    const int blk = wg >> 6;                        // 0..7
    const int j   = wg & 63;
    const int bnt = (blk & 1) * 8 + (j & 7);        // 0..15
    const int bmt = (blk >> 1) * 8 + (j >> 3);      // 0..31
    const int bm = bmt * 128, bn = bnt * 64;

    const int lane = tid & 63;
    const int wv   = tid >> 6;
    const int wr   = wv >> 1;            // M-half
    const int wk   = wv & 1;             // K-half
    const int lrow = lane & 15;
    const int kg   = (lane >> 4) * 8;
    const int sr   = lane >> 3;          // staging row within 8-row chunk
    const int sc   = (lane & 7) * 8;     // staging bf16 col (0..56)

    f4v acc[4][4] = {};

    // A: 16 chunks of 1KB (4/wave); B: 8 chunks (2/wave) -> 6 gll16/wave
#define STG2(bufi, k0)                                                        \
    { _Pragma("unroll")                                                       \
      for (int i_ = 0; i_ < 4; ++i_) {                                        \
        const int ch_  = wv * 4 + i_;                                         \
        const int row_ = ch_ * 8 + sr;                                        \
        gll16(&MH[(size_t)(bm + row_) * TL + (k0) + sc],                      \
              lds + (bufi) * 24576 + ch_ * 1024);                             \
      }                                                                       \
      _Pragma("unroll")                                                       \
      for (int i_ = 0; i_ < 2; ++i_) {                                        \
        const int ch_  = wv * 2 + i_;                                         \
        const int row_ = ch_ * 8 + sr;                                        \
        gll16(&PTH[(size_t)(bn + row_) * TL + (k0) + sc],                     \
              lds + (bufi) * 24576 + 16384 + ch_ * 1024);                     \
      } }

    STG2(0, 0);
    for (int t = 0; t < 32; ++t) {
        const int cur = t & 1;
        if (t < 31) {
            STG2(cur ^ 1, (t + 1) * 64);
            asm volatile("s_waitcnt vmcnt(6)" ::: "memory");
        } else {
            asm volatile("s_waitcnt vmcnt(0)" ::: "memory");
        }
        __builtin_amdgcn_s_barrier();
        __builtin_amdgcn_sched_barrier(0);

        s8v a[4], bfr[4];
        #pragma unroll
        for (int mf = 0; mf < 4; ++mf)
            a[mf] = *reinterpret_cast<const s8v*>(
                lds + cur * 24576 + ((wr * 64 + mf * 16 + lrow) * 64 + wk * 32 + kg) * 2);
        #pragma unroll
        for (int nf = 0; nf < 4; ++nf)
            bfr[nf] = *reinterpret_cast<const s8v*>(
                lds + cur * 24576 + 16384 + ((nf * 16 + lrow) * 64 + wk * 32 + kg) * 2);
        #pragma unroll
        for (int mf = 0; mf < 4; ++mf)
            #pragma unroll
            for (int nf = 0; nf < 4; ++nf)
                acc[mf][nf] = __builtin_amdgcn_mfma_f32_16x16x32_bf16(a[mf], bfr[nf], acc[mf][nf], 0, 0, 0);

        __builtin_amdgcn_sched_barrier(0);
        asm volatile("s_waitcnt lgkmcnt(0)" ::: "memory");
        __builtin_amdgcn_s_barrier();
    }
#undef STG2

    // ---- cross-K reduce: wk==1 waves dump acc, wk==0 waves add + write ----
    float* red = (float*)lds;   // [2 wr][64][64] f32 = 32 KB
    if (wk == 1) {
        #pragma unroll
        for (int mf = 0; mf < 4; ++mf)
            #pragma unroll
            for (int nf = 0; nf < 4; ++nf)
                #pragma unroll
                for (int r = 0; r < 4; ++r) {
                    const int rowB = mf * 16 + (lane >> 4) * 4 + r;
                    const int colB = nf * 16 + lrow;
                    red[wr * 4096 + rowB * 64 + colB] = acc[mf][nf][r];
                }
    }
    __syncthreads();
    if (wk == 0) {
        #pragma unroll
        for (int nf = 0; nf < 4; ++nf) {
            const int col = bn + nf * 16 + lrow;
            if (col >= Cv) continue;
            #pragma unroll
            for (int mf = 0; mf < 4; ++mf) {
                #pragma unroll
                for (int r = 0; r < 4; ++r) {
                    const int rowB = mf * 16 + (lane >> 4) * 4 + r;
                    const float v = acc[mf][nf][r] + red[wr * 4096 + rowB * 64 + nf * 16 + lrow];
                    out[(size_t)(bm + wr * 64 + rowB) * Cv + col] = v;
                }
            }
        }
    }
}

// ---------------------------------------------------------------------------
extern "C" void kernel_launch(void* const* d_in, const int* in_sizes, int n_in,
                              void* d_out, int out_size, void* d_ws, size_t ws_size,
                              hipStream_t stream) {
    const float* x  = (const float*)d_in[0];  // [B, D]
    const float* sw = (const float*)d_in[1];  // [T, NI, D]
    const float* sb = (const float*)d_in[2];  // [T, NI]
    const float* ll = (const float*)d_in[3];  // [T, NL, C]
    const float* tw = (const float*)d_in[4];  // [T]
    const float* lt = (const float*)d_in[5];  // scalar

    float* out  = (float*)d_out;              // [B, C]
    float* ws   = (float*)d_ws;
    _Float16* Xh = (_Float16*)(ws + OFF_XH);
    _Float16* Wh = (_Float16*)(ws + OFF_WH);
    unsigned short* MH  = (unsigned short*)(ws + OFF_MH);
    unsigned short* PTH = (unsigned short*)(ws + OFF_PTH);

    k_prep<<<6144, 256, 0, stream>>>(x, sw, Xh, Wh);
    k_gemm1mu_lf<<<768, 256, 0, stream>>>(Xh, Wh, sb, tw, lt, ll, MH, PTH);
    k_gemm2<<<512, 256, 0, stream>>>(MH, PTH, out);
}